// Round 1
// baseline (1081.689 us; speedup 1.0000x reference)
//
#include <hip/hip_runtime.h>

#define DH 128

// ---------------- CSR build ----------------
__global__ void hist_kernel(const int* __restrict__ dst, int* __restrict__ counts, int E) {
  int i = blockIdx.x * blockDim.x + threadIdx.x;
  if (i < E) atomicAdd(&counts[dst[i]], 1);
}

#define SCAN_T 256
#define SCAN_V 8
#define SCAN_CHUNK (SCAN_T * SCAN_V)

__global__ void scan1_kernel(const int* __restrict__ counts, int* __restrict__ partial,
                             int* __restrict__ bsums, int n) {
  __shared__ int lds[SCAN_T];
  int t = threadIdx.x;
  int base = blockIdx.x * SCAN_CHUNK + t * SCAN_V;
  int v[SCAN_V];
  int s = 0;
#pragma unroll
  for (int j = 0; j < SCAN_V; ++j) {
    int idx = base + j;
    v[j] = (idx < n) ? counts[idx] : 0;
    s += v[j];
  }
  lds[t] = s;
  __syncthreads();
  for (int off = 1; off < SCAN_T; off <<= 1) {
    int add = (t >= off) ? lds[t - off] : 0;
    __syncthreads();
    lds[t] += add;
    __syncthreads();
  }
  int run = (t ? lds[t - 1] : 0);
#pragma unroll
  for (int j = 0; j < SCAN_V; ++j) {
    int idx = base + j;
    if (idx < n) partial[idx] = run;
    run += v[j];
  }
  if (t == SCAN_T - 1) bsums[blockIdx.x] = lds[SCAN_T - 1];
}

__global__ void scan2_kernel(int* __restrict__ bsums, int nb, int* __restrict__ total) {
  __shared__ int lds[SCAN_T];
  int t = threadIdx.x;
  int v = (t < nb) ? bsums[t] : 0;
  lds[t] = v;
  __syncthreads();
  for (int off = 1; off < SCAN_T; off <<= 1) {
    int add = (t >= off) ? lds[t - off] : 0;
    __syncthreads();
    lds[t] += add;
    __syncthreads();
  }
  if (t < nb) bsums[t] = lds[t] - v;  // exclusive
  if (t == SCAN_T - 1) *total = lds[SCAN_T - 1];
}

__global__ void scan3_kernel(int* __restrict__ rowptr, const int* __restrict__ bsums, int n) {
  int i = blockIdx.x * blockDim.x + threadIdx.x;
  if (i < n) rowptr[i] += bsums[i / SCAN_CHUNK];
}

__global__ void scatter_kernel(const int* __restrict__ src, const int* __restrict__ dst,
                               const int* __restrict__ rowptr, int* __restrict__ cursor,
                               int* __restrict__ ssrc, int E) {
  int i = blockIdx.x * blockDim.x + threadIdx.x;
  if (i < E) {
    int d = dst[i];
    int p = rowptr[d] + atomicAdd(&cursor[d], 1);
    ssrc[p] = src[i];
  }
}

// ---------------- GEMM: h = x @ W  (fp32, W staged in LDS) ----------------
__global__ __launch_bounds__(256) void gemm_kernel(const float* __restrict__ x,
                                                   const float* __restrict__ W,
                                                   float* __restrict__ h, int M) {
  __shared__ float Ws[DH * DH];  // 64 KB
  {
    const float4* Wg = (const float4*)W;
    float4* Wl = (float4*)Ws;
    for (int i = threadIdx.x; i < DH * DH / 4; i += 256) Wl[i] = Wg[i];
  }
  __syncthreads();
  int cg = threadIdx.x & 15;   // 16 col groups x 8 cols
  int rg = threadIdx.x >> 4;   // 16 row groups x 4 rows
  int r0 = blockIdx.x * 64 + rg * 4;
  float acc[4][8];
#pragma unroll
  for (int j = 0; j < 4; ++j)
#pragma unroll
    for (int c = 0; c < 8; ++c) acc[j][c] = 0.f;

  for (int k0 = 0; k0 < DH; k0 += 4) {
    float4 xv[4];
#pragma unroll
    for (int j = 0; j < 4; ++j) {
      if (r0 + j < M)
        xv[j] = *(const float4*)(x + (size_t)(r0 + j) * DH + k0);
      else
        xv[j] = make_float4(0.f, 0.f, 0.f, 0.f);
    }
#pragma unroll
    for (int kk = 0; kk < 4; ++kk) {
      const float4 w0 = *(const float4*)&Ws[(k0 + kk) * DH + cg * 8];
      const float4 w1 = *(const float4*)&Ws[(k0 + kk) * DH + cg * 8 + 4];
#pragma unroll
      for (int j = 0; j < 4; ++j) {
        float xs = (&xv[j].x)[kk];
        acc[j][0] += xs * w0.x; acc[j][1] += xs * w0.y;
        acc[j][2] += xs * w0.z; acc[j][3] += xs * w0.w;
        acc[j][4] += xs * w1.x; acc[j][5] += xs * w1.y;
        acc[j][6] += xs * w1.z; acc[j][7] += xs * w1.w;
      }
    }
  }
#pragma unroll
  for (int j = 0; j < 4; ++j) {
    if (r0 + j < M) {
      float* hp = h + (size_t)(r0 + j) * DH + cg * 8;
      *(float4*)hp = make_float4(acc[j][0], acc[j][1], acc[j][2], acc[j][3]);
      *(float4*)(hp + 4) = make_float4(acc[j][4], acc[j][5], acc[j][6], acc[j][7]);
    }
  }
}

// ---------------- el/er = h . attn_l , h . attn_r (one wave per node) ----------------
__global__ __launch_bounds__(256) void elr_kernel(const float* __restrict__ h,
                                                  const float* __restrict__ al,
                                                  const float* __restrict__ ar,
                                                  float* __restrict__ el, float* __restrict__ er,
                                                  int M) {
  int wid = (blockIdx.x * blockDim.x + threadIdx.x) >> 6;
  int lane = threadIdx.x & 63;
  if (wid >= M) return;
  float2 hv = ((const float2*)(h + (size_t)wid * DH))[lane];
  float2 alv = ((const float2*)al)[lane];
  float2 arv = ((const float2*)ar)[lane];
  float l = hv.x * alv.x + hv.y * alv.y;
  float r = hv.x * arv.x + hv.y * arv.y;
#pragma unroll
  for (int off = 32; off; off >>= 1) {
    l += __shfl_xor(l, off);
    r += __shfl_xor(r, off);
  }
  if (lane == 0) {
    el[wid] = l;
    er[wid] = r;
  }
}

// ---------------- fused edge-softmax + aggregation (one wave per dst node) ----------------
__global__ __launch_bounds__(256) void agg_kernel(const float* __restrict__ h,
                                                  const float* __restrict__ el,
                                                  const float* __restrict__ er,
                                                  const int* __restrict__ rowptr,
                                                  const int* __restrict__ ssrc,
                                                  const float* __restrict__ bias,
                                                  float* __restrict__ out, int M) {
  int wid = (blockIdx.x * blockDim.x + threadIdx.x) >> 6;  // node id
  int lane = threadIdx.x & 63;
  if (wid >= M) return;
  int begin = rowptr[wid], end = rowptr[wid + 1];
  float2 b2 = ((const float2*)bias)[lane];
  float2* outp = (float2*)(out + (size_t)wid * DH) + lane;
  if (begin == end) {  // zero in-degree: out = bias
    *outp = b2;
    return;
  }
  float er_d = er[wid];
  // pass 1: segment max of leaky_relu scores
  float mx = -1e30f;
  for (int e = begin + lane; e < end; e += 64) {
    float s = el[ssrc[e]] + er_d;
    s = s > 0.f ? s : 0.2f * s;
    mx = fmaxf(mx, s);
  }
#pragma unroll
  for (int off = 32; off; off >>= 1) mx = fmaxf(mx, __shfl_xor(mx, off));
  // pass 2: weighted gather-accumulate (serial over edges, wave-wide over channels)
  float acc0 = 0.f, acc1 = 0.f, ssum = 0.f;
  for (int e = begin; e < end; ++e) {
    int s = ssrc[e];
    float sc = el[s] + er_d;
    sc = sc > 0.f ? sc : 0.2f * sc;
    float w = __expf(sc - mx);
    ssum += w;
    float2 hv = ((const float2*)(h + (size_t)s * DH))[lane];
    acc0 += w * hv.x;
    acc1 += w * hv.y;
  }
  float inv = 1.f / ssum;
  *outp = make_float2(acc0 * inv + b2.x, acc1 * inv + b2.y);
}

extern "C" void kernel_launch(void* const* d_in, const int* in_sizes, int n_in,
                              void* d_out, int out_size, void* d_ws, size_t ws_size,
                              hipStream_t stream) {
  const float* feat = (const float*)d_in[0];
  const int* src = (const int*)d_in[1];
  const int* dst = (const int*)d_in[2];
  const int N = in_sizes[0] / DH;  // 100000
  const int E = in_sizes[1];       // 1600000
  const float* W[3]  = {(const float*)d_in[3], (const float*)d_in[7],  (const float*)d_in[11]};
  const float* al[3] = {(const float*)d_in[4], (const float*)d_in[8],  (const float*)d_in[12]};
  const float* ar[3] = {(const float*)d_in[5], (const float*)d_in[9],  (const float*)d_in[13]};
  const float* bi[3] = {(const float*)d_in[6], (const float*)d_in[10], (const float*)d_in[14]};

  // workspace layout (~59 MB)
  char* ws = (char*)d_ws;
  size_t off = 0;
  auto alloc = [&](size_t bytes) {
    void* p = ws + off;
    off = (off + bytes + 255) & ~(size_t)255;
    return p;
  };
  float* hbuf  = (float*)alloc((size_t)N * DH * sizeof(float));
  float* el    = (float*)alloc((size_t)N * sizeof(float));
  float* er    = (float*)alloc((size_t)N * sizeof(float));
  int* rowptr  = (int*)alloc((size_t)(N + 1) * sizeof(int));
  int* counts  = (int*)alloc((size_t)N * sizeof(int));
  int* bsums   = (int*)alloc(256 * sizeof(int));
  int* ssrc    = (int*)alloc((size_t)E * sizeof(int));
  float* outbuf = (float*)d_out;

  // ---- CSR by dst (shared by all 3 layers) ----
  hipMemsetAsync(counts, 0, (size_t)N * sizeof(int), stream);
  hist_kernel<<<(E + 255) / 256, 256, 0, stream>>>(dst, counts, E);
  int nb = (N + SCAN_CHUNK - 1) / SCAN_CHUNK;  // 49
  scan1_kernel<<<nb, SCAN_T, 0, stream>>>(counts, rowptr, bsums, N);
  scan2_kernel<<<1, SCAN_T, 0, stream>>>(bsums, nb, rowptr + N);
  scan3_kernel<<<(N + 255) / 256, 256, 0, stream>>>(rowptr, bsums, N);
  hipMemsetAsync(counts, 0, (size_t)N * sizeof(int), stream);
  scatter_kernel<<<(E + 255) / 256, 256, 0, stream>>>(src, dst, rowptr, counts, ssrc, E);

  // ---- 3 GAT layers; d_out ping-pongs as the inter-layer node buffer ----
  const float* x = feat;
  for (int l = 0; l < 3; ++l) {
    gemm_kernel<<<(N + 63) / 64, 256, 0, stream>>>(x, W[l], hbuf, N);
    elr_kernel<<<(N + 3) / 4, 256, 0, stream>>>(hbuf, al[l], ar[l], el, er, N);
    agg_kernel<<<(N + 3) / 4, 256, 0, stream>>>(hbuf, el, er, rowptr, ssrc, bi[l], outbuf, N);
    x = outbuf;
  }
}

// Round 2
// 789.043 us; speedup vs baseline: 1.3709x; 1.3709x over previous
//
#include <hip/hip_runtime.h>

#define DH 128

typedef __attribute__((ext_vector_type(8))) short s16x8;
typedef __attribute__((ext_vector_type(4))) float f32x4;

__device__ __forceinline__ ushort f2bf(float x) {
  uint u = __builtin_bit_cast(uint, x);
  u = (u + 0x7FFF + ((u >> 16) & 1)) >> 16;  // RTNE
  return (ushort)u;
}
__device__ __forceinline__ float bfl2f(uint u) {  // low ushort -> float
  return __builtin_bit_cast(float, u << 16);
}
__device__ __forceinline__ float bfh2f(uint u) {  // high ushort -> float
  return __builtin_bit_cast(float, u & 0xFFFF0000u);
}

// ---------------- CSR build ----------------
__global__ void hist_kernel(const int* __restrict__ dst, int* __restrict__ counts, int E) {
  int i = blockIdx.x * blockDim.x + threadIdx.x;
  if (i < E) atomicAdd(&counts[dst[i]], 1);
}

#define SCAN_T 256
#define SCAN_V 8
#define SCAN_CHUNK (SCAN_T * SCAN_V)

__global__ void scan1_kernel(const int* __restrict__ counts, int* __restrict__ partial,
                             int* __restrict__ bsums, int n) {
  __shared__ int lds[SCAN_T];
  int t = threadIdx.x;
  int base = blockIdx.x * SCAN_CHUNK + t * SCAN_V;
  int v[SCAN_V];
  int s = 0;
#pragma unroll
  for (int j = 0; j < SCAN_V; ++j) {
    int idx = base + j;
    v[j] = (idx < n) ? counts[idx] : 0;
    s += v[j];
  }
  lds[t] = s;
  __syncthreads();
  for (int off = 1; off < SCAN_T; off <<= 1) {
    int add = (t >= off) ? lds[t - off] : 0;
    __syncthreads();
    lds[t] += add;
    __syncthreads();
  }
  int run = (t ? lds[t - 1] : 0);
#pragma unroll
  for (int j = 0; j < SCAN_V; ++j) {
    int idx = base + j;
    if (idx < n) partial[idx] = run;
    run += v[j];
  }
  if (t == SCAN_T - 1) bsums[blockIdx.x] = lds[SCAN_T - 1];
}

__global__ void scan2_kernel(int* __restrict__ bsums, int nb, int* __restrict__ total) {
  __shared__ int lds[SCAN_T];
  int t = threadIdx.x;
  int v = (t < nb) ? bsums[t] : 0;
  lds[t] = v;
  __syncthreads();
  for (int off = 1; off < SCAN_T; off <<= 1) {
    int add = (t >= off) ? lds[t - off] : 0;
    __syncthreads();
    lds[t] += add;
    __syncthreads();
  }
  if (t < nb) bsums[t] = lds[t] - v;  // exclusive
  if (t == SCAN_T - 1) *total = lds[SCAN_T - 1];
}

__global__ void scan3_kernel(int* __restrict__ rowptr, const int* __restrict__ bsums, int n) {
  int i = blockIdx.x * blockDim.x + threadIdx.x;
  if (i < n) rowptr[i] += bsums[i / SCAN_CHUNK];
}

__global__ void scatter_kernel(const int* __restrict__ src, const int* __restrict__ dst,
                               const int* __restrict__ rowptr, int* __restrict__ cursor,
                               int* __restrict__ ssrc, int E) {
  int i = blockIdx.x * blockDim.x + threadIdx.x;
  if (i < E) {
    int d = dst[i];
    int p = rowptr[d] + atomicAdd(&cursor[d], 1);
    ssrc[p] = src[i];
  }
}

// ---------------- W -> Wt bf16 transpose prep (one block) ----------------
__global__ __launch_bounds__(256) void wt_kernel(const float* __restrict__ W,
                                                 ushort* __restrict__ Wtb) {
  int t = threadIdx.x;
  int col = t >> 1;
  int kh = (t & 1) * 64;
  for (int kb = 0; kb < 8; ++kb) {
    int k0 = kh + kb * 8;
    s16x8 v;
#pragma unroll
    for (int j = 0; j < 8; ++j) v[j] = (short)f2bf(W[(size_t)(k0 + j) * DH + col]);
    *(s16x8*)(&Wtb[(size_t)col * DH + k0]) = v;
  }
}

// ---------------- GEMM: hb(bf16) = x(fp32) @ W ; fused el/er ----------------
// block = 256 threads = 4 waves; tile 64 rows x 128 cols; mfma 16x16x32 bf16
__global__ __launch_bounds__(256) void gemm_kernel(const float* __restrict__ x,
                                                   const ushort* __restrict__ Wtb,
                                                   const float* __restrict__ al,
                                                   const float* __restrict__ ar,
                                                   ushort* __restrict__ hb,
                                                   float* __restrict__ el,
                                                   float* __restrict__ er, int M) {
  __shared__ ushort As[64 * DH];   // 16 KB, XOR-swizzled 16B blocks
  __shared__ ushort Bs[DH * DH];   // 32 KB, Wt[col][k], XOR-swizzled
  int t = threadIdx.x;
  int R0 = blockIdx.x * 64;

  // stage B (bf16, already transposed): 2048 16B-blocks
  for (int i = t; i < 2048; i += 256) {
    int col = i >> 4, kb = i & 15;
    s16x8 v = *(const s16x8*)(Wtb + (size_t)col * DH + kb * 8);
    *(s16x8*)(&Bs[col * DH + ((kb ^ (col & 15)) * 8)]) = v;
  }
  // stage A (fp32 -> bf16): 1024 16B-blocks
  for (int i = t; i < 1024; i += 256) {
    int row = i >> 4, kb = i & 15;
    int gr = R0 + row;
    s16x8 v;
    if (gr < M) {
      const float4* p = (const float4*)(x + (size_t)gr * DH + kb * 8);
      float4 a = p[0], b = p[1];
      v[0] = (short)f2bf(a.x); v[1] = (short)f2bf(a.y);
      v[2] = (short)f2bf(a.z); v[3] = (short)f2bf(a.w);
      v[4] = (short)f2bf(b.x); v[5] = (short)f2bf(b.y);
      v[6] = (short)f2bf(b.z); v[7] = (short)f2bf(b.w);
    } else {
      v = (s16x8)0;
    }
    *(s16x8*)(&As[row * DH + ((kb ^ (row & 15)) * 8)]) = v;
  }
  __syncthreads();

  int w = t >> 6, lane = t & 63;
  int li = lane & 15, lq = lane >> 4;
  f32x4 acc[8] = {};
  int arow = w * 16 + li;
#pragma unroll
  for (int kc = 0; kc < 4; ++kc) {
    int kb = kc * 4 + lq;
    s16x8 af = *(const s16x8*)(&As[arow * DH + ((kb ^ (arow & 15)) * 8)]);
#pragma unroll
    for (int cf = 0; cf < 8; ++cf) {
      int bcol = cf * 16 + li;
      s16x8 bf = *(const s16x8*)(&Bs[bcol * DH + ((kb ^ (bcol & 15)) * 8)]);
      acc[cf] = __builtin_amdgcn_mfma_f32_16x16x32_bf16(af, bf, acc[cf], 0, 0, 0);
    }
  }

  int Rw = R0 + w * 16;
  // fused el/er: lane holds D[row=lq*4+r][col=cf*16+li]
  float alv[8], arv[8];
#pragma unroll
  for (int cf = 0; cf < 8; ++cf) {
    alv[cf] = al[cf * 16 + li];
    arv[cf] = ar[cf * 16 + li];
  }
#pragma unroll
  for (int r = 0; r < 4; ++r) {
    float sl = 0.f, sr = 0.f;
#pragma unroll
    for (int cf = 0; cf < 8; ++cf) {
      sl += acc[cf][r] * alv[cf];
      sr += acc[cf][r] * arv[cf];
    }
#pragma unroll
    for (int off = 1; off <= 8; off <<= 1) {
      sl += __shfl_xor(sl, off);
      sr += __shfl_xor(sr, off);
    }
    int grow = Rw + lq * 4 + r;
    if (li == 0 && grow < M) {
      el[grow] = sl;
      er[grow] = sr;
    }
  }

  // h store via LDS repack (reuse As; each wave uses its own 4 KB row range)
  ushort* hl = &As[w * 16 * DH];
#pragma unroll
  for (int cf = 0; cf < 8; ++cf)
#pragma unroll
    for (int r = 0; r < 4; ++r) hl[(lq * 4 + r) * DH + cf * 16 + li] = f2bf(acc[cf][r]);
  __syncthreads();
#pragma unroll
  for (int p = 0; p < 4; ++p) {
    int row = lane >> 2;
    int blk = (lane & 3) + p * 4;
    s16x8 v = *(const s16x8*)(&hl[row * DH + blk * 8]);
    int grow = Rw + row;
    if (grow < M) *(s16x8*)(hb + (size_t)grow * DH + blk * 8) = v;
  }
}

// ---------------- fused edge-softmax + aggregation (one wave per dst node) ----------------
__global__ __launch_bounds__(256) void agg_kernel(const ushort* __restrict__ hb,
                                                  const float* __restrict__ el,
                                                  const float* __restrict__ er,
                                                  const int* __restrict__ rowptr,
                                                  const int* __restrict__ ssrc,
                                                  const float* __restrict__ bias,
                                                  float* __restrict__ out, int M) {
  int wid = (blockIdx.x * blockDim.x + threadIdx.x) >> 6;  // node id
  int lane = threadIdx.x & 63;
  if (wid >= M) return;
  int begin = rowptr[wid], end = rowptr[wid + 1];
  float2 b2 = ((const float2*)bias)[lane];
  float2* outp = (float2*)(out + (size_t)wid * DH) + lane;
  if (begin == end) {  // zero in-degree: out = bias
    *outp = b2;
    return;
  }
  float er_d = er[wid];
  // pass 1: segment max of leaky_relu scores
  float mx = -1e30f;
  for (int e = begin + lane; e < end; e += 64) {
    float s = el[ssrc[e]] + er_d;
    s = s > 0.f ? s : 0.2f * s;
    mx = fmaxf(mx, s);
  }
#pragma unroll
  for (int off = 32; off; off >>= 1) mx = fmaxf(mx, __shfl_xor(mx, off));
  // pass 2: weighted gather-accumulate (bf16 rows: 4 B/lane)
  float acc0 = 0.f, acc1 = 0.f, ssum = 0.f;
  for (int e = begin; e < end; ++e) {
    int s = ssrc[e];
    float sc = el[s] + er_d;
    sc = sc > 0.f ? sc : 0.2f * sc;
    float wgt = __expf(sc - mx);
    ssum += wgt;
    uint u = ((const uint*)(hb + (size_t)s * DH))[lane];
    acc0 += wgt * bfl2f(u);
    acc1 += wgt * bfh2f(u);
  }
  float inv = 1.f / ssum;
  *outp = make_float2(acc0 * inv + b2.x, acc1 * inv + b2.y);
}

extern "C" void kernel_launch(void* const* d_in, const int* in_sizes, int n_in,
                              void* d_out, int out_size, void* d_ws, size_t ws_size,
                              hipStream_t stream) {
  const float* feat = (const float*)d_in[0];
  const int* src = (const int*)d_in[1];
  const int* dst = (const int*)d_in[2];
  const int N = in_sizes[0] / DH;  // 100000
  const int E = in_sizes[1];       // 1600000
  const float* W[3]  = {(const float*)d_in[3], (const float*)d_in[7],  (const float*)d_in[11]};
  const float* al[3] = {(const float*)d_in[4], (const float*)d_in[8],  (const float*)d_in[12]};
  const float* ar[3] = {(const float*)d_in[5], (const float*)d_in[9],  (const float*)d_in[13]};
  const float* bi[3] = {(const float*)d_in[6], (const float*)d_in[10], (const float*)d_in[14]};

  // workspace layout (~34 MB)
  char* ws = (char*)d_ws;
  size_t off = 0;
  auto alloc = [&](size_t bytes) {
    void* p = ws + off;
    off = (off + bytes + 255) & ~(size_t)255;
    return p;
  };
  ushort* hb   = (ushort*)alloc((size_t)N * DH * sizeof(ushort));
  float* el    = (float*)alloc((size_t)N * sizeof(float));
  float* er    = (float*)alloc((size_t)N * sizeof(float));
  int* rowptr  = (int*)alloc((size_t)(N + 1) * sizeof(int));
  int* counts  = (int*)alloc((size_t)N * sizeof(int));
  int* bsums   = (int*)alloc(256 * sizeof(int));
  int* ssrc    = (int*)alloc((size_t)E * sizeof(int));
  ushort* Wtb  = (ushort*)alloc((size_t)DH * DH * sizeof(ushort));
  float* outbuf = (float*)d_out;

  // ---- CSR by dst (shared by all 3 layers) ----
  hipMemsetAsync(counts, 0, (size_t)N * sizeof(int), stream);
  hist_kernel<<<(E + 255) / 256, 256, 0, stream>>>(dst, counts, E);
  int nb = (N + SCAN_CHUNK - 1) / SCAN_CHUNK;  // 49
  scan1_kernel<<<nb, SCAN_T, 0, stream>>>(counts, rowptr, bsums, N);
  scan2_kernel<<<1, SCAN_T, 0, stream>>>(bsums, nb, rowptr + N);
  scan3_kernel<<<(N + 255) / 256, 256, 0, stream>>>(rowptr, bsums, N);
  hipMemsetAsync(counts, 0, (size_t)N * sizeof(int), stream);
  scatter_kernel<<<(E + 255) / 256, 256, 0, stream>>>(src, dst, rowptr, counts, ssrc, E);

  // ---- 3 GAT layers; d_out serves as the fp32 inter-layer node buffer ----
  // (gemm fully consumes the fp32 x buffer before agg overwrites it)
  const float* x = feat;
  for (int l = 0; l < 3; ++l) {
    wt_kernel<<<1, 256, 0, stream>>>(W[l], Wtb);
    gemm_kernel<<<(N + 63) / 64, 256, 0, stream>>>(x, Wtb, al[l], ar[l], hb, el, er, N);
    agg_kernel<<<(N + 3) / 4, 256, 0, stream>>>(hb, el, er, rowptr, ssrc, bi[l], outbuf, N);
    x = outbuf;
  }
}

// Round 3
// 470.616 us; speedup vs baseline: 2.2985x; 1.6766x over previous
//
#include <hip/hip_runtime.h>

#define DH 128

typedef __attribute__((ext_vector_type(8))) short s16x8;
typedef __attribute__((ext_vector_type(4))) float f32x4;

__device__ __forceinline__ ushort f2bf(float x) {
  uint u = __builtin_bit_cast(uint, x);
  u = (u + 0x7FFF + ((u >> 16) & 1)) >> 16;  // RTNE
  return (ushort)u;
}
__device__ __forceinline__ float bfl2f(uint u) {  // low ushort -> float
  return __builtin_bit_cast(float, u << 16);
}
__device__ __forceinline__ float bfh2f(uint u) {  // high ushort -> float
  return __builtin_bit_cast(float, u & 0xFFFF0000u);
}

// ---------------- CSR build ----------------
__global__ void hist_kernel(const int* __restrict__ dst, int* __restrict__ counts, int E) {
  int i = blockIdx.x * blockDim.x + threadIdx.x;
  if (i < E) atomicAdd(&counts[dst[i]], 1);
}

#define SCAN_T 256
#define SCAN_V 8
#define SCAN_CHUNK (SCAN_T * SCAN_V)

__global__ void scan1_kernel(const int* __restrict__ counts, int* __restrict__ partial,
                             int* __restrict__ bsums, int n) {
  __shared__ int lds[SCAN_T];
  int t = threadIdx.x;
  int base = blockIdx.x * SCAN_CHUNK + t * SCAN_V;
  int v[SCAN_V];
  int s = 0;
#pragma unroll
  for (int j = 0; j < SCAN_V; ++j) {
    int idx = base + j;
    v[j] = (idx < n) ? counts[idx] : 0;
    s += v[j];
  }
  lds[t] = s;
  __syncthreads();
  for (int off = 1; off < SCAN_T; off <<= 1) {
    int add = (t >= off) ? lds[t - off] : 0;
    __syncthreads();
    lds[t] += add;
    __syncthreads();
  }
  int run = (t ? lds[t - 1] : 0);
#pragma unroll
  for (int j = 0; j < SCAN_V; ++j) {
    int idx = base + j;
    if (idx < n) partial[idx] = run;
    run += v[j];
  }
  if (t == SCAN_T - 1) bsums[blockIdx.x] = lds[SCAN_T - 1];
}

__global__ void scan2_kernel(int* __restrict__ bsums, int nb, int* __restrict__ total) {
  __shared__ int lds[SCAN_T];
  int t = threadIdx.x;
  int v = (t < nb) ? bsums[t] : 0;
  lds[t] = v;
  __syncthreads();
  for (int off = 1; off < SCAN_T; off <<= 1) {
    int add = (t >= off) ? lds[t - off] : 0;
    __syncthreads();
    lds[t] += add;
    __syncthreads();
  }
  if (t < nb) bsums[t] = lds[t] - v;  // exclusive
  if (t == SCAN_T - 1) *total = lds[SCAN_T - 1];
}

__global__ void scan3_kernel(int* __restrict__ rowptr, const int* __restrict__ bsums, int n) {
  int i = blockIdx.x * blockDim.x + threadIdx.x;
  if (i < n) rowptr[i] += bsums[i / SCAN_CHUNK];
}

__global__ void scatter_kernel(const int* __restrict__ src, const int* __restrict__ dst,
                               const int* __restrict__ rowptr, int* __restrict__ cursor,
                               int* __restrict__ ssrc, int E) {
  int i = blockIdx.x * blockDim.x + threadIdx.x;
  if (i < E) {
    int d = dst[i];
    int p = rowptr[d] + atomicAdd(&cursor[d], 1);
    ssrc[p] = src[i];
  }
}

// ---------------- W -> Wt bf16 transpose prep (parallel) ----------------
__global__ __launch_bounds__(256) void wt_kernel(const float* __restrict__ W,
                                                 ushort* __restrict__ Wtb) {
  int i = blockIdx.x * 256 + threadIdx.x;  // 16384 elements
  int col = i >> 7, k = i & 127;
  Wtb[(size_t)col * DH + k] = f2bf(W[(size_t)k * DH + col]);
}

// ---------------- GEMM: hb(bf16) = x(fp32) @ W ; fused el/er ----------------
// block = 256 threads = 4 waves; tile 64 rows x 128 cols; mfma 16x16x32 bf16
__global__ __launch_bounds__(256) void gemm_kernel(const float* __restrict__ x,
                                                   const ushort* __restrict__ Wtb,
                                                   const float* __restrict__ al,
                                                   const float* __restrict__ ar,
                                                   ushort* __restrict__ hb,
                                                   float* __restrict__ el,
                                                   float* __restrict__ er, int M) {
  __shared__ ushort As[64 * DH];   // 16 KB, XOR-swizzled 16B blocks
  __shared__ ushort Bs[DH * DH];   // 32 KB, Wt[col][k], XOR-swizzled
  int t = threadIdx.x;
  int R0 = blockIdx.x * 64;

  // stage B (bf16, already transposed): 2048 16B-blocks
  for (int i = t; i < 2048; i += 256) {
    int col = i >> 4, kb = i & 15;
    s16x8 v = *(const s16x8*)(Wtb + (size_t)col * DH + kb * 8);
    *(s16x8*)(&Bs[col * DH + ((kb ^ (col & 15)) * 8)]) = v;
  }
  // stage A (fp32 -> bf16): 1024 16B-blocks
  for (int i = t; i < 1024; i += 256) {
    int row = i >> 4, kb = i & 15;
    int gr = R0 + row;
    s16x8 v;
    if (gr < M) {
      const float4* p = (const float4*)(x + (size_t)gr * DH + kb * 8);
      float4 a = p[0], b = p[1];
      v[0] = (short)f2bf(a.x); v[1] = (short)f2bf(a.y);
      v[2] = (short)f2bf(a.z); v[3] = (short)f2bf(a.w);
      v[4] = (short)f2bf(b.x); v[5] = (short)f2bf(b.y);
      v[6] = (short)f2bf(b.z); v[7] = (short)f2bf(b.w);
    } else {
      v = (s16x8)0;
    }
    *(s16x8*)(&As[row * DH + ((kb ^ (row & 15)) * 8)]) = v;
  }
  __syncthreads();

  int w = t >> 6, lane = t & 63;
  int li = lane & 15, lq = lane >> 4;
  f32x4 acc[8] = {};
  int arow = w * 16 + li;
#pragma unroll
  for (int kc = 0; kc < 4; ++kc) {
    int kb = kc * 4 + lq;
    s16x8 af = *(const s16x8*)(&As[arow * DH + ((kb ^ (arow & 15)) * 8)]);
#pragma unroll
    for (int cf = 0; cf < 8; ++cf) {
      int bcol = cf * 16 + li;
      s16x8 bf = *(const s16x8*)(&Bs[bcol * DH + ((kb ^ (bcol & 15)) * 8)]);
      acc[cf] = __builtin_amdgcn_mfma_f32_16x16x32_bf16(af, bf, acc[cf], 0, 0, 0);
    }
  }

  int Rw = R0 + w * 16;
  // fused el/er: lane holds D[row=lq*4+r][col=cf*16+li]
  float alv[8], arv[8];
#pragma unroll
  for (int cf = 0; cf < 8; ++cf) {
    alv[cf] = al[cf * 16 + li];
    arv[cf] = ar[cf * 16 + li];
  }
#pragma unroll
  for (int r = 0; r < 4; ++r) {
    float sl = 0.f, sr = 0.f;
#pragma unroll
    for (int cf = 0; cf < 8; ++cf) {
      sl += acc[cf][r] * alv[cf];
      sr += acc[cf][r] * arv[cf];
    }
#pragma unroll
    for (int off = 1; off <= 8; off <<= 1) {
      sl += __shfl_xor(sl, off);
      sr += __shfl_xor(sr, off);
    }
    int grow = Rw + lq * 4 + r;
    if (li == 0 && grow < M) {
      el[grow] = sl;
      er[grow] = sr;
    }
  }

  // h store via LDS repack (reuse As; each wave uses its own 4 KB row range)
  ushort* hl = &As[w * 16 * DH];
#pragma unroll
  for (int cf = 0; cf < 8; ++cf)
#pragma unroll
    for (int r = 0; r < 4; ++r) hl[(lq * 4 + r) * DH + cf * 16 + li] = f2bf(acc[cf][r]);
  __syncthreads();
#pragma unroll
  for (int p = 0; p < 4; ++p) {
    int row = lane >> 2;
    int blk = (lane & 3) + p * 4;
    s16x8 v = *(const s16x8*)(&hl[row * DH + blk * 8]);
    int grow = Rw + row;
    if (grow < M) *(s16x8*)(hb + (size_t)grow * DH + blk * 8) = v;
  }
}

// ---------------- fused edge-softmax + aggregation (one wave per dst node) ----------------
// Lane-parallel score/exp prologue; serial channel loop does ONLY row gathers,
// 8-deep unrolled for memory-level parallelism.
__global__ __launch_bounds__(256) void agg_kernel(const ushort* __restrict__ hb,
                                                  const float* __restrict__ el,
                                                  const float* __restrict__ er,
                                                  const int* __restrict__ rowptr,
                                                  const int* __restrict__ ssrc,
                                                  const float* __restrict__ bias,
                                                  float* __restrict__ out, int M) {
  int wid = (blockIdx.x * blockDim.x + threadIdx.x) >> 6;  // node id
  int lane = threadIdx.x & 63;
  if (wid >= M) return;
  int begin = rowptr[wid], end = rowptr[wid + 1];
  float2 b2 = ((const float2*)bias)[lane];
  float2* outp = (float2*)(out + (size_t)wid * DH) + lane;
  int deg = end - begin;
  if (deg == 0) {  // zero in-degree: out = bias
    *outp = b2;
    return;
  }
  float er_d = er[wid];
  float acc0 = 0.f, acc1 = 0.f;
  float inv;

  if (deg <= 64) {
    // lane j owns edge begin+j: index, el-gather, leaky, exp all lane-parallel
    int e = begin + lane;
    int idx = (e < end) ? ssrc[e] : 0;
    float sc = -1e30f;
    if (e < end) {
      sc = el[idx] + er_d;
      sc = sc > 0.f ? sc : 0.2f * sc;
    }
    float mx = sc;
#pragma unroll
    for (int off = 32; off; off >>= 1) mx = fmaxf(mx, __shfl_xor(mx, off));
    float wgt = (e < end) ? __expf(sc - mx) : 0.f;
    float ssum = wgt;
#pragma unroll
    for (int off = 32; off; off >>= 1) ssum += __shfl_xor(ssum, off);

    int j = 0;
    for (; j + 8 <= deg; j += 8) {
      uint u[8];
      float wg[8];
#pragma unroll
      for (int k = 0; k < 8; ++k) {
        int s = __shfl(idx, j + k);
        wg[k] = __shfl(wgt, j + k);
        u[k] = ((const uint*)(hb + (size_t)s * DH))[lane];
      }
#pragma unroll
      for (int k = 0; k < 8; ++k) {
        acc0 += wg[k] * bfl2f(u[k]);
        acc1 += wg[k] * bfh2f(u[k]);
      }
    }
    for (; j < deg; ++j) {
      int s = __shfl(idx, j);
      float wg = __shfl(wgt, j);
      uint u = ((const uint*)(hb + (size_t)s * DH))[lane];
      acc0 += wg * bfl2f(u);
      acc1 += wg * bfh2f(u);
    }
    inv = 1.f / ssum;
  } else {
    // rare high-degree path: chunk edges by 64
    float mx = -1e30f;
    for (int e = begin + lane; e < end; e += 64) {
      float s = el[ssrc[e]] + er_d;
      s = s > 0.f ? s : 0.2f * s;
      mx = fmaxf(mx, s);
    }
#pragma unroll
    for (int off = 32; off; off >>= 1) mx = fmaxf(mx, __shfl_xor(mx, off));
    float ssum_l = 0.f;
    for (int base = begin; base < end; base += 64) {
      int n = min(64, end - base);
      int e = base + lane;
      int idx = 0;
      float wgt = 0.f;
      if (lane < n) {
        idx = ssrc[e];
        float sc = el[idx] + er_d;
        sc = sc > 0.f ? sc : 0.2f * sc;
        wgt = __expf(sc - mx);
      }
      ssum_l += wgt;
      int j = 0;
      for (; j + 4 <= n; j += 4) {
        uint u[4];
        float wg[4];
#pragma unroll
        for (int k = 0; k < 4; ++k) {
          int s = __shfl(idx, j + k);
          wg[k] = __shfl(wgt, j + k);
          u[k] = ((const uint*)(hb + (size_t)s * DH))[lane];
        }
#pragma unroll
        for (int k = 0; k < 4; ++k) {
          acc0 += wg[k] * bfl2f(u[k]);
          acc1 += wg[k] * bfh2f(u[k]);
        }
      }
      for (; j < n; ++j) {
        int s = __shfl(idx, j);
        float wg = __shfl(wgt, j);
        uint u = ((const uint*)(hb + (size_t)s * DH))[lane];
        acc0 += wg * bfl2f(u);
        acc1 += wg * bfh2f(u);
      }
    }
#pragma unroll
    for (int off = 32; off; off >>= 1) ssum_l += __shfl_xor(ssum_l, off);
    inv = 1.f / ssum_l;
  }
  *outp = make_float2(acc0 * inv + b2.x, acc1 * inv + b2.y);
}

extern "C" void kernel_launch(void* const* d_in, const int* in_sizes, int n_in,
                              void* d_out, int out_size, void* d_ws, size_t ws_size,
                              hipStream_t stream) {
  const float* feat = (const float*)d_in[0];
  const int* src = (const int*)d_in[1];
  const int* dst = (const int*)d_in[2];
  const int N = in_sizes[0] / DH;  // 100000
  const int E = in_sizes[1];       // 1600000
  const float* W[3]  = {(const float*)d_in[3], (const float*)d_in[7],  (const float*)d_in[11]};
  const float* al[3] = {(const float*)d_in[4], (const float*)d_in[8],  (const float*)d_in[12]};
  const float* ar[3] = {(const float*)d_in[5], (const float*)d_in[9],  (const float*)d_in[13]};
  const float* bi[3] = {(const float*)d_in[6], (const float*)d_in[10], (const float*)d_in[14]};

  // workspace layout (~34 MB)
  char* ws = (char*)d_ws;
  size_t off = 0;
  auto alloc = [&](size_t bytes) {
    void* p = ws + off;
    off = (off + bytes + 255) & ~(size_t)255;
    return p;
  };
  ushort* hb   = (ushort*)alloc((size_t)N * DH * sizeof(ushort));
  float* el    = (float*)alloc((size_t)N * sizeof(float));
  float* er    = (float*)alloc((size_t)N * sizeof(float));
  int* rowptr  = (int*)alloc((size_t)(N + 1) * sizeof(int));
  int* counts  = (int*)alloc((size_t)N * sizeof(int));
  int* bsums   = (int*)alloc(256 * sizeof(int));
  int* ssrc    = (int*)alloc((size_t)E * sizeof(int));
  ushort* Wtb  = (ushort*)alloc((size_t)DH * DH * sizeof(ushort));
  float* outbuf = (float*)d_out;

  // ---- CSR by dst (shared by all 3 layers) ----
  hipMemsetAsync(counts, 0, (size_t)N * sizeof(int), stream);
  hist_kernel<<<(E + 255) / 256, 256, 0, stream>>>(dst, counts, E);
  int nb = (N + SCAN_CHUNK - 1) / SCAN_CHUNK;  // 49
  scan1_kernel<<<nb, SCAN_T, 0, stream>>>(counts, rowptr, bsums, N);
  scan2_kernel<<<1, SCAN_T, 0, stream>>>(bsums, nb, rowptr + N);
  scan3_kernel<<<(N + 255) / 256, 256, 0, stream>>>(rowptr, bsums, N);
  hipMemsetAsync(counts, 0, (size_t)N * sizeof(int), stream);
  scatter_kernel<<<(E + 255) / 256, 256, 0, stream>>>(src, dst, rowptr, counts, ssrc, E);

  // ---- 3 GAT layers; d_out serves as the fp32 inter-layer node buffer ----
  // (gemm fully consumes the fp32 x buffer before agg overwrites it)
  const float* x = feat;
  for (int l = 0; l < 3; ++l) {
    wt_kernel<<<64, 256, 0, stream>>>(W[l], Wtb);
    gemm_kernel<<<(N + 63) / 64, 256, 0, stream>>>(x, Wtb, al[l], ar[l], hb, el, er, N);
    agg_kernel<<<(N + 3) / 4, 256, 0, stream>>>(hb, el, er, rowptr, ssrc, bi[l], outbuf, N);
    x = outbuf;
  }
}

// Round 4
// 344.754 us; speedup vs baseline: 3.1376x; 1.3651x over previous
//
#include <hip/hip_runtime.h>

#define DH 128
#define NBMAX 1024   // max coarse bins (N <= 131072)
#define BCH 8192     // edges per block in CSR build

typedef __attribute__((ext_vector_type(8))) short s16x8;
typedef __attribute__((ext_vector_type(4))) float f32x4;

__device__ __forceinline__ ushort f2bf(float x) {
  uint u = __builtin_bit_cast(uint, x);
  u = (u + 0x7FFF + ((u >> 16) & 1)) >> 16;  // RTNE
  return (ushort)u;
}
__device__ __forceinline__ float bfl2f(uint u) {  // low ushort -> float
  return __builtin_bit_cast(float, u << 16);
}
__device__ __forceinline__ float bfh2f(uint u) {  // high ushort -> float
  return __builtin_bit_cast(float, u & 0xFFFF0000u);
}

// ================= CSR build: LDS-binned counting sort by dst =================
// coarse bin = dst >> 7 (128 nodes/bin). chist/ccur padded x16 ints (64B) to
// kill atomic line contention.

__global__ __launch_bounds__(256) void chist_kernel(const int* __restrict__ dst,
                                                    int* __restrict__ chist, int E, int NB) {
  __shared__ int h[NBMAX];
  int t = threadIdx.x;
  for (int i = t; i < NB; i += 256) h[i] = 0;
  __syncthreads();
  int base = blockIdx.x * BCH;
  int n = min(BCH, E - base);
  for (int i = t; i < n; i += 256) atomicAdd(&h[((uint)dst[base + i]) >> 7], 1);
  __syncthreads();
  for (int i = t; i < NB; i += 256)
    if (h[i]) atomicAdd(&chist[i * 16], h[i]);
}

__global__ __launch_bounds__(256) void cscan_kernel(const int* __restrict__ chist,
                                                    int* __restrict__ cbase, int* __restrict__ ccur,
                                                    int* __restrict__ rowptr, int N, int NB, int E) {
  __shared__ int lds[256];
  int t = threadIdx.x;
  int v[4], s = 0;
#pragma unroll
  for (int j = 0; j < 4; ++j) {
    int idx = t * 4 + j;
    v[j] = (idx < NB) ? chist[idx * 16] : 0;
    s += v[j];
  }
  lds[t] = s;
  __syncthreads();
  for (int off = 1; off < 256; off <<= 1) {
    int add = (t >= off) ? lds[t - off] : 0;
    __syncthreads();
    lds[t] += add;
    __syncthreads();
  }
  int run = t ? lds[t - 1] : 0;
#pragma unroll
  for (int j = 0; j < 4; ++j) {
    int idx = t * 4 + j;
    if (idx < NB) {
      cbase[idx] = run;
      ccur[idx * 16] = run;
    }
    run += v[j];
  }
  if (t == 255) cbase[NB] = lds[255];
  if (t == 0) rowptr[N] = E;
}

__global__ __launch_bounds__(256) void binscat_kernel(const int* __restrict__ src,
                                                      const int* __restrict__ dst,
                                                      int* __restrict__ ccur,
                                                      uint2* __restrict__ puv, int E, int NB) {
  __shared__ int h[NBMAX];
  __shared__ int gb[NBMAX];
  int t = threadIdx.x;
  int base = blockIdx.x * BCH;
  int n = min(BCH, E - base);
  for (int i = t; i < NB; i += 256) h[i] = 0;
  __syncthreads();
  for (int i = t; i < n; i += 256) atomicAdd(&h[((uint)dst[base + i]) >> 7], 1);
  __syncthreads();
  // reserve a contiguous run per bin for this block; reset h as local cursor
  for (int i = t; i < NB; i += 256) {
    int c = h[i];
    gb[i] = c ? atomicAdd(&ccur[i * 16], c) : 0;
    h[i] = 0;
  }
  __syncthreads();
  for (int i = t; i < n; i += 256) {
    int d = dst[base + i];
    int b = ((uint)d) >> 7;
    int p = gb[b] + atomicAdd(&h[b], 1);
    puv[p] = make_uint2((uint)src[base + i], (uint)d);
  }
}

__global__ __launch_bounds__(256) void finesort_kernel(const uint2* __restrict__ puv,
                                                       const int* __restrict__ cbase,
                                                       int* __restrict__ rowptr,
                                                       int* __restrict__ ssrc, int N) {
  int b = blockIdx.x;
  int base = cbase[b];
  int cnt = cbase[b + 1] - base;
  __shared__ int ncnt[128], nincl[128], noff[128];
  int t = threadIdx.x;
  if (t < 128) ncnt[t] = 0;
  __syncthreads();
  for (int i = t; i < cnt; i += 256) atomicAdd(&ncnt[puv[base + i].y & 127], 1);
  __syncthreads();
  if (t < 128) nincl[t] = ncnt[t];
  __syncthreads();
  for (int off = 1; off < 128; off <<= 1) {
    int add = (t < 128 && t >= off) ? nincl[t - off] : 0;
    __syncthreads();
    if (t < 128) nincl[t] += add;
    __syncthreads();
  }
  if (t < 128) {
    noff[t] = nincl[t] - ncnt[t];
    int node = (b << 7) + t;
    if (node < N) rowptr[node] = base + noff[t];
    ncnt[t] = 0;  // reuse as cursor
  }
  __syncthreads();
  for (int i = t; i < cnt; i += 256) {
    uint2 e = puv[base + i];
    int ln = e.y & 127;
    int p = base + noff[ln] + atomicAdd(&ncnt[ln], 1);
    ssrc[p] = (int)e.x;
  }
}

// ---------------- W -> Wt bf16 transpose prep (parallel) ----------------
__global__ __launch_bounds__(256) void wt_kernel(const float* __restrict__ W,
                                                 ushort* __restrict__ Wtb) {
  int i = blockIdx.x * 256 + threadIdx.x;  // 16384 elements
  int col = i >> 7, k = i & 127;
  Wtb[(size_t)col * DH + k] = f2bf(W[(size_t)k * DH + col]);
}

// ---------------- GEMM: hb(bf16) = x @ W ; fused el/er ----------------
// block = 256 threads = 4 waves; tile 64 rows x 128 cols; mfma 16x16x32 bf16
// XF32: x is fp32 (layer 0 input); else x is bf16 (inter-layer buffer)
template <bool XF32>
__global__ __launch_bounds__(256) void gemm_kernel(const void* __restrict__ xin,
                                                   const ushort* __restrict__ Wtb,
                                                   const float* __restrict__ al,
                                                   const float* __restrict__ ar,
                                                   ushort* __restrict__ hb,
                                                   float* __restrict__ el,
                                                   float* __restrict__ er, int M) {
  __shared__ ushort As[64 * DH];   // 16 KB, XOR-swizzled 16B blocks
  __shared__ ushort Bs[DH * DH];   // 32 KB, Wt[col][k], XOR-swizzled
  int t = threadIdx.x;
  int R0 = blockIdx.x * 64;

  // stage B (bf16, already transposed): 2048 16B-blocks
  for (int i = t; i < 2048; i += 256) {
    int col = i >> 4, kb = i & 15;
    s16x8 v = *(const s16x8*)(Wtb + (size_t)col * DH + kb * 8);
    *(s16x8*)(&Bs[col * DH + ((kb ^ (col & 15)) * 8)]) = v;
  }
  // stage A: 1024 16B-blocks
  for (int i = t; i < 1024; i += 256) {
    int row = i >> 4, kb = i & 15;
    int gr = R0 + row;
    s16x8 v;
    if (gr < M) {
      if constexpr (XF32) {
        const float4* p = (const float4*)((const float*)xin + (size_t)gr * DH + kb * 8);
        float4 a = p[0], b = p[1];
        v[0] = (short)f2bf(a.x); v[1] = (short)f2bf(a.y);
        v[2] = (short)f2bf(a.z); v[3] = (short)f2bf(a.w);
        v[4] = (short)f2bf(b.x); v[5] = (short)f2bf(b.y);
        v[6] = (short)f2bf(b.z); v[7] = (short)f2bf(b.w);
      } else {
        v = *(const s16x8*)((const ushort*)xin + (size_t)gr * DH + kb * 8);
      }
    } else {
      v = (s16x8)0;
    }
    *(s16x8*)(&As[row * DH + ((kb ^ (row & 15)) * 8)]) = v;
  }
  __syncthreads();

  int w = t >> 6, lane = t & 63;
  int li = lane & 15, lq = lane >> 4;
  f32x4 acc[8] = {};
  int arow = w * 16 + li;
#pragma unroll
  for (int kc = 0; kc < 4; ++kc) {
    int kb = kc * 4 + lq;
    s16x8 af = *(const s16x8*)(&As[arow * DH + ((kb ^ (arow & 15)) * 8)]);
#pragma unroll
    for (int cf = 0; cf < 8; ++cf) {
      int bcol = cf * 16 + li;
      s16x8 bf = *(const s16x8*)(&Bs[bcol * DH + ((kb ^ (bcol & 15)) * 8)]);
      acc[cf] = __builtin_amdgcn_mfma_f32_16x16x32_bf16(af, bf, acc[cf], 0, 0, 0);
    }
  }

  int Rw = R0 + w * 16;
  // fused el/er: lane holds D[row=lq*4+r][col=cf*16+li]
  float alv[8], arv[8];
#pragma unroll
  for (int cf = 0; cf < 8; ++cf) {
    alv[cf] = al[cf * 16 + li];
    arv[cf] = ar[cf * 16 + li];
  }
#pragma unroll
  for (int r = 0; r < 4; ++r) {
    float sl = 0.f, sr = 0.f;
#pragma unroll
    for (int cf = 0; cf < 8; ++cf) {
      sl += acc[cf][r] * alv[cf];
      sr += acc[cf][r] * arv[cf];
    }
#pragma unroll
    for (int off = 1; off <= 8; off <<= 1) {
      sl += __shfl_xor(sl, off);
      sr += __shfl_xor(sr, off);
    }
    int grow = Rw + lq * 4 + r;
    if (li == 0 && grow < M) {
      el[grow] = sl;
      er[grow] = sr;
    }
  }

  // h store via LDS repack (reuse As; each wave uses its own 4 KB row range)
  ushort* hl = &As[w * 16 * DH];
#pragma unroll
  for (int cf = 0; cf < 8; ++cf)
#pragma unroll
    for (int r = 0; r < 4; ++r) hl[(lq * 4 + r) * DH + cf * 16 + li] = f2bf(acc[cf][r]);
  __syncthreads();
#pragma unroll
  for (int p = 0; p < 4; ++p) {
    int row = lane >> 2;
    int blk = (lane & 3) + p * 4;
    s16x8 v = *(const s16x8*)(&hl[row * DH + blk * 8]);
    int grow = Rw + row;
    if (grow < M) *(s16x8*)(hb + (size_t)grow * DH + blk * 8) = v;
  }
}

// ---------------- fused edge-softmax + aggregation (one wave per dst node) ----------------
// FINAL=0: write bf16 xb (next layer input); FINAL=1: write fp32 d_out.
template <int FINAL>
__global__ __launch_bounds__(256) void agg_kernel(const ushort* __restrict__ hb,
                                                  const float* __restrict__ el,
                                                  const float* __restrict__ er,
                                                  const int* __restrict__ rowptr,
                                                  const int* __restrict__ ssrc,
                                                  const float* __restrict__ bias,
                                                  void* __restrict__ outv, int M) {
  int wid = (blockIdx.x * blockDim.x + threadIdx.x) >> 6;  // node id
  int lane = threadIdx.x & 63;
  if (wid >= M) return;
  int begin = rowptr[wid], end = rowptr[wid + 1];
  float2 b2 = ((const float2*)bias)[lane];
  int deg = end - begin;
  float acc0 = 0.f, acc1 = 0.f;
  float inv = 0.f;

  if (deg > 0 && deg <= 64) {
    // lane j owns edge begin+j: index, el-gather, leaky, exp all lane-parallel
    int e = begin + lane;
    int idx = (e < end) ? ssrc[e] : 0;
    float sc = -1e30f;
    if (e < end) {
      sc = el[idx] + er[wid];
      sc = sc > 0.f ? sc : 0.2f * sc;
    }
    float mx = sc;
#pragma unroll
    for (int off = 32; off; off >>= 1) mx = fmaxf(mx, __shfl_xor(mx, off));
    float wgt = (e < end) ? __expf(sc - mx) : 0.f;
    float ssum = wgt;
#pragma unroll
    for (int off = 32; off; off >>= 1) ssum += __shfl_xor(ssum, off);

    int j = 0;
    for (; j + 16 <= deg; j += 16) {
      uint u[16];
      float wg[16];
#pragma unroll
      for (int k = 0; k < 16; ++k) {
        int s = __shfl(idx, j + k);
        wg[k] = __shfl(wgt, j + k);
        u[k] = ((const uint*)(hb + (size_t)s * DH))[lane];
      }
#pragma unroll
      for (int k = 0; k < 16; ++k) {
        acc0 += wg[k] * bfl2f(u[k]);
        acc1 += wg[k] * bfh2f(u[k]);
      }
    }
    for (; j + 4 <= deg; j += 4) {
      uint u[4];
      float wg[4];
#pragma unroll
      for (int k = 0; k < 4; ++k) {
        int s = __shfl(idx, j + k);
        wg[k] = __shfl(wgt, j + k);
        u[k] = ((const uint*)(hb + (size_t)s * DH))[lane];
      }
#pragma unroll
      for (int k = 0; k < 4; ++k) {
        acc0 += wg[k] * bfl2f(u[k]);
        acc1 += wg[k] * bfh2f(u[k]);
      }
    }
    for (; j < deg; ++j) {
      int s = __shfl(idx, j);
      float wg = __shfl(wgt, j);
      uint u = ((const uint*)(hb + (size_t)s * DH))[lane];
      acc0 += wg * bfl2f(u);
      acc1 += wg * bfh2f(u);
    }
    inv = 1.f / ssum;
  } else if (deg > 64) {
    float er_d = er[wid];
    float mx = -1e30f;
    for (int e = begin + lane; e < end; e += 64) {
      float s = el[ssrc[e]] + er_d;
      s = s > 0.f ? s : 0.2f * s;
      mx = fmaxf(mx, s);
    }
#pragma unroll
    for (int off = 32; off; off >>= 1) mx = fmaxf(mx, __shfl_xor(mx, off));
    float ssum_l = 0.f;
    for (int base = begin; base < end; base += 64) {
      int n = min(64, end - base);
      int e = base + lane;
      int idx = 0;
      float wgt = 0.f;
      if (lane < n) {
        idx = ssrc[e];
        float sc = el[idx] + er_d;
        sc = sc > 0.f ? sc : 0.2f * sc;
        wgt = __expf(sc - mx);
      }
      ssum_l += wgt;
      int j = 0;
      for (; j + 4 <= n; j += 4) {
        uint u[4];
        float wg[4];
#pragma unroll
        for (int k = 0; k < 4; ++k) {
          int s = __shfl(idx, j + k);
          wg[k] = __shfl(wgt, j + k);
          u[k] = ((const uint*)(hb + (size_t)s * DH))[lane];
        }
#pragma unroll
        for (int k = 0; k < 4; ++k) {
          acc0 += wg[k] * bfl2f(u[k]);
          acc1 += wg[k] * bfh2f(u[k]);
        }
      }
      for (; j < n; ++j) {
        int s = __shfl(idx, j);
        float wg = __shfl(wgt, j);
        uint u = ((const uint*)(hb + (size_t)s * DH))[lane];
        acc0 += wg * bfl2f(u);
        acc1 += wg * bfh2f(u);
      }
    }
#pragma unroll
    for (int off = 32; off; off >>= 1) ssum_l += __shfl_xor(ssum_l, off);
    inv = 1.f / ssum_l;
  }
  // deg==0: acc=0, inv=0 -> out = bias
  float o0 = acc0 * inv + b2.x;
  float o1 = acc1 * inv + b2.y;
  if constexpr (FINAL) {
    ((float2*)((float*)outv + (size_t)wid * DH))[lane] = make_float2(o0, o1);
  } else {
    uint p = (uint)f2bf(o0) | ((uint)f2bf(o1) << 16);
    ((uint*)((ushort*)outv + (size_t)wid * DH))[lane] = p;
  }
}

extern "C" void kernel_launch(void* const* d_in, const int* in_sizes, int n_in,
                              void* d_out, int out_size, void* d_ws, size_t ws_size,
                              hipStream_t stream) {
  const float* feat = (const float*)d_in[0];
  const int* src = (const int*)d_in[1];
  const int* dst = (const int*)d_in[2];
  const int N = in_sizes[0] / DH;  // 100000
  const int E = in_sizes[1];       // 1600000
  const int NB = (N + 127) >> 7;   // 782 coarse bins
  const float* W[3]  = {(const float*)d_in[3], (const float*)d_in[7],  (const float*)d_in[11]};
  const float* al[3] = {(const float*)d_in[4], (const float*)d_in[8],  (const float*)d_in[12]};
  const float* ar[3] = {(const float*)d_in[5], (const float*)d_in[9],  (const float*)d_in[13]};
  const float* bi[3] = {(const float*)d_in[6], (const float*)d_in[10], (const float*)d_in[14]};

  // workspace layout (~59 MB)
  char* ws = (char*)d_ws;
  size_t off = 0;
  auto alloc = [&](size_t bytes) {
    void* p = ws + off;
    off = (off + bytes + 255) & ~(size_t)255;
    return p;
  };
  ushort* hb   = (ushort*)alloc((size_t)N * DH * sizeof(ushort));  // 25.6 MB
  ushort* xb   = (ushort*)alloc((size_t)N * DH * sizeof(ushort));  // 25.6 MB
  float* el    = (float*)alloc((size_t)N * sizeof(float));
  float* er    = (float*)alloc((size_t)N * sizeof(float));
  int* rowptr  = (int*)alloc((size_t)(N + 1) * sizeof(int));
  int* ssrc    = (int*)alloc((size_t)E * sizeof(int));             // 6.4 MB
  ushort* Wtb  = (ushort*)alloc((size_t)DH * DH * sizeof(ushort));
  int* chist   = (int*)alloc((size_t)NBMAX * 16 * sizeof(int));    // 64 KB padded
  int* cbase   = (int*)alloc((size_t)(NBMAX + 1) * sizeof(int));
  int* ccur    = (int*)alloc((size_t)NBMAX * 16 * sizeof(int));    // 64 KB padded
  uint2* puv   = (uint2*)hb;  // 12.8 MB alias: dead before first gemm writes hb

  // ---- CSR by dst (shared by all 3 layers): LDS-binned counting sort ----
  hipMemsetAsync(chist, 0, (size_t)NBMAX * 16 * sizeof(int), stream);
  int ebl = (E + BCH - 1) / BCH;  // 196
  chist_kernel<<<ebl, 256, 0, stream>>>(dst, chist, E, NB);
  cscan_kernel<<<1, 256, 0, stream>>>(chist, cbase, ccur, rowptr, N, NB, E);
  binscat_kernel<<<ebl, 256, 0, stream>>>(src, dst, ccur, puv, E, NB);
  finesort_kernel<<<NB, 256, 0, stream>>>(puv, cbase, rowptr, ssrc, N);

  // ---- 3 GAT layers; xb (bf16) is the inter-layer node buffer ----
  for (int l = 0; l < 3; ++l) {
    wt_kernel<<<64, 256, 0, stream>>>(W[l], Wtb);
    if (l == 0)
      gemm_kernel<true><<<(N + 63) / 64, 256, 0, stream>>>(feat, Wtb, al[l], ar[l], hb, el, er, N);
    else
      gemm_kernel<false><<<(N + 63) / 64, 256, 0, stream>>>(xb, Wtb, al[l], ar[l], hb, el, er, N);
    if (l < 2)
      agg_kernel<0><<<(N + 3) / 4, 256, 0, stream>>>(hb, el, er, rowptr, ssrc, bi[l], xb, N);
    else
      agg_kernel<1><<<(N + 3) / 4, 256, 0, stream>>>(hb, el, er, rowptr, ssrc, bi[l], d_out, N);
  }
}

// Round 5
// 340.979 us; speedup vs baseline: 3.1723x; 1.0111x over previous
//
#include <hip/hip_runtime.h>

#define DH 128
#define NBMAX 1024   // max coarse bins (N <= 131072)
#define BCH 8192     // edges per block in CSR build

typedef __attribute__((ext_vector_type(8))) short s16x8;
typedef __attribute__((ext_vector_type(4))) float f32x4;

__device__ __forceinline__ ushort f2bf(float x) {
  uint u = __builtin_bit_cast(uint, x);
  u = (u + 0x7FFF + ((u >> 16) & 1)) >> 16;  // RTNE
  return (ushort)u;
}
__device__ __forceinline__ float bfl2f(uint u) {  // low ushort -> float
  return __builtin_bit_cast(float, u << 16);
}
__device__ __forceinline__ float bfh2f(uint u) {  // high ushort -> float
  return __builtin_bit_cast(float, u & 0xFFFF0000u);
}

// ================= CSR build: LDS-binned counting sort by dst =================
// coarse bin = dst >> 7 (128 nodes/bin). chist/ccur padded x16 ints (64B) to
// kill atomic line contention. puv packs (localnode<<25)|src in one uint.

__global__ __launch_bounds__(256) void chist_kernel(const int* __restrict__ dst,
                                                    int* __restrict__ chist, int E, int NB) {
  __shared__ int h[NBMAX];
  int t = threadIdx.x;
  for (int i = t; i < NB; i += 256) h[i] = 0;
  __syncthreads();
  int base = blockIdx.x * BCH;
  int n = min(BCH, E - base);
  for (int i = t; i < n; i += 256) atomicAdd(&h[((uint)dst[base + i]) >> 7], 1);
  __syncthreads();
  for (int i = t; i < NB; i += 256)
    if (h[i]) atomicAdd(&chist[i * 16], h[i]);
}

__global__ __launch_bounds__(256) void cscan_kernel(const int* __restrict__ chist,
                                                    int* __restrict__ cbase, int* __restrict__ ccur,
                                                    int* __restrict__ rowptr, int N, int NB, int E) {
  __shared__ int lds[256];
  int t = threadIdx.x;
  int v[4], s = 0;
#pragma unroll
  for (int j = 0; j < 4; ++j) {
    int idx = t * 4 + j;
    v[j] = (idx < NB) ? chist[idx * 16] : 0;
    s += v[j];
  }
  lds[t] = s;
  __syncthreads();
  for (int off = 1; off < 256; off <<= 1) {
    int add = (t >= off) ? lds[t - off] : 0;
    __syncthreads();
    lds[t] += add;
    __syncthreads();
  }
  int run = t ? lds[t - 1] : 0;
#pragma unroll
  for (int j = 0; j < 4; ++j) {
    int idx = t * 4 + j;
    if (idx < NB) {
      cbase[idx] = run;
      ccur[idx * 16] = run;
    }
    run += v[j];
  }
  if (t == 255) cbase[NB] = lds[255];
  if (t == 0) rowptr[N] = E;
}

__global__ __launch_bounds__(256) void binscat_kernel(const int* __restrict__ src,
                                                      const int* __restrict__ dst,
                                                      int* __restrict__ ccur,
                                                      uint* __restrict__ puv, int E, int NB) {
  __shared__ int h[NBMAX];
  __shared__ int gb[NBMAX];
  int t = threadIdx.x;
  int base = blockIdx.x * BCH;
  int n = min(BCH, E - base);
  for (int i = t; i < NB; i += 256) h[i] = 0;
  __syncthreads();
  for (int i = t; i < n; i += 256) atomicAdd(&h[((uint)dst[base + i]) >> 7], 1);
  __syncthreads();
  // reserve a contiguous run per bin for this block; reset h as local cursor
  for (int i = t; i < NB; i += 256) {
    int c = h[i];
    gb[i] = c ? atomicAdd(&ccur[i * 16], c) : 0;
    h[i] = 0;
  }
  __syncthreads();
  for (int i = t; i < n; i += 256) {
    uint d = (uint)dst[base + i];
    int b = d >> 7;
    int p = gb[b] + atomicAdd(&h[b], 1);
    puv[p] = ((d & 127u) << 25) | (uint)src[base + i];
  }
}

__global__ __launch_bounds__(256) void finesort_kernel(const uint* __restrict__ puv,
                                                       const int* __restrict__ cbase,
                                                       int* __restrict__ rowptr,
                                                       int* __restrict__ ssrc, int N) {
  int b = blockIdx.x;
  int base = cbase[b];
  int cnt = cbase[b + 1] - base;
  __shared__ int ncnt[128], nincl[128], noff[128];
  int t = threadIdx.x;
  if (t < 128) ncnt[t] = 0;
  __syncthreads();
  for (int i = t; i < cnt; i += 256) atomicAdd(&ncnt[puv[base + i] >> 25], 1);
  __syncthreads();
  if (t < 128) nincl[t] = ncnt[t];
  __syncthreads();
  for (int off = 1; off < 128; off <<= 1) {
    int add = (t < 128 && t >= off) ? nincl[t - off] : 0;
    __syncthreads();
    if (t < 128) nincl[t] += add;
    __syncthreads();
  }
  if (t < 128) {
    noff[t] = nincl[t] - ncnt[t];
    int node = (b << 7) + t;
    if (node < N) rowptr[node] = base + noff[t];
    ncnt[t] = 0;  // reuse as cursor
  }
  __syncthreads();
  for (int i = t; i < cnt; i += 256) {
    uint e = puv[base + i];
    int ln = e >> 25;
    int p = base + noff[ln] + atomicAdd(&ncnt[ln], 1);
    ssrc[p] = (int)(e & 0x1FFFFFFu);
  }
}

// ---------------- W -> Wt bf16 transpose prep (parallel) ----------------
__global__ __launch_bounds__(256) void wt_kernel(const float* __restrict__ W,
                                                 ushort* __restrict__ Wtb) {
  int i = blockIdx.x * 256 + threadIdx.x;  // 16384 elements
  int col = i >> 7, k = i & 127;
  Wtb[(size_t)col * DH + k] = f2bf(W[(size_t)k * DH + col]);
}

// ---------------- GEMM: hb(bf16) = x @ W ; fused el/er ----------------
// block = 256 threads = 4 waves; tile 64 rows x 128 cols; mfma 16x16x32 bf16
// XF32: x is fp32 (layer 0 input); else x is bf16 (inter-layer buffer)
template <bool XF32>
__global__ __launch_bounds__(256) void gemm_kernel(const void* __restrict__ xin,
                                                   const ushort* __restrict__ Wtb,
                                                   const float* __restrict__ al,
                                                   const float* __restrict__ ar,
                                                   ushort* __restrict__ hb,
                                                   float* __restrict__ el,
                                                   float* __restrict__ er, int M) {
  __shared__ ushort As[64 * DH];   // 16 KB, XOR-swizzled 16B blocks
  __shared__ ushort Bs[DH * DH];   // 32 KB, Wt[col][k], XOR-swizzled
  int t = threadIdx.x;
  int R0 = blockIdx.x * 64;

  // stage B (bf16, already transposed): 2048 16B-blocks
  for (int i = t; i < 2048; i += 256) {
    int col = i >> 4, kb = i & 15;
    s16x8 v = *(const s16x8*)(Wtb + (size_t)col * DH + kb * 8);
    *(s16x8*)(&Bs[col * DH + ((kb ^ (col & 15)) * 8)]) = v;
  }
  // stage A: 1024 16B-blocks
  for (int i = t; i < 1024; i += 256) {
    int row = i >> 4, kb = i & 15;
    int gr = R0 + row;
    s16x8 v;
    if (gr < M) {
      if constexpr (XF32) {
        const float4* p = (const float4*)((const float*)xin + (size_t)gr * DH + kb * 8);
        float4 a = p[0], b = p[1];
        v[0] = (short)f2bf(a.x); v[1] = (short)f2bf(a.y);
        v[2] = (short)f2bf(a.z); v[3] = (short)f2bf(a.w);
        v[4] = (short)f2bf(b.x); v[5] = (short)f2bf(b.y);
        v[6] = (short)f2bf(b.z); v[7] = (short)f2bf(b.w);
      } else {
        v = *(const s16x8*)((const ushort*)xin + (size_t)gr * DH + kb * 8);
      }
    } else {
      v = (s16x8)0;
    }
    *(s16x8*)(&As[row * DH + ((kb ^ (row & 15)) * 8)]) = v;
  }
  __syncthreads();

  int w = t >> 6, lane = t & 63;
  int li = lane & 15, lq = lane >> 4;
  f32x4 acc[8] = {};
  int arow = w * 16 + li;
#pragma unroll
  for (int kc = 0; kc < 4; ++kc) {
    int kb = kc * 4 + lq;
    s16x8 af = *(const s16x8*)(&As[arow * DH + ((kb ^ (arow & 15)) * 8)]);
#pragma unroll
    for (int cf = 0; cf < 8; ++cf) {
      int bcol = cf * 16 + li;
      s16x8 bf = *(const s16x8*)(&Bs[bcol * DH + ((kb ^ (bcol & 15)) * 8)]);
      acc[cf] = __builtin_amdgcn_mfma_f32_16x16x32_bf16(af, bf, acc[cf], 0, 0, 0);
    }
  }

  int Rw = R0 + w * 16;
  // fused el/er: lane holds D[row=lq*4+r][col=cf*16+li]
  float alv[8], arv[8];
#pragma unroll
  for (int cf = 0; cf < 8; ++cf) {
    alv[cf] = al[cf * 16 + li];
    arv[cf] = ar[cf * 16 + li];
  }
#pragma unroll
  for (int r = 0; r < 4; ++r) {
    float sl = 0.f, sr = 0.f;
#pragma unroll
    for (int cf = 0; cf < 8; ++cf) {
      sl += acc[cf][r] * alv[cf];
      sr += acc[cf][r] * arv[cf];
    }
#pragma unroll
    for (int off = 1; off <= 8; off <<= 1) {
      sl += __shfl_xor(sl, off);
      sr += __shfl_xor(sr, off);
    }
    int grow = Rw + lq * 4 + r;
    if (li == 0 && grow < M) {
      el[grow] = sl;
      er[grow] = sr;
    }
  }

  // h store via LDS repack (reuse As; each wave uses its own 4 KB row range)
  ushort* hl = &As[w * 16 * DH];
#pragma unroll
  for (int cf = 0; cf < 8; ++cf)
#pragma unroll
    for (int r = 0; r < 4; ++r) hl[(lq * 4 + r) * DH + cf * 16 + li] = f2bf(acc[cf][r]);
  __syncthreads();
#pragma unroll
  for (int p = 0; p < 4; ++p) {
    int row = lane >> 2;
    int blk = (lane & 3) + p * 4;
    s16x8 v = *(const s16x8*)(&hl[row * DH + blk * 8]);
    int grow = Rw + row;
    if (grow < M) *(s16x8*)(hb + (size_t)grow * DH + blk * 8) = v;
  }
}

// ---------------- fused edge-softmax + aggregation (one wave per dst node) ----------------
// Quad-edge gathers: 16 lanes x 16B cover one 256B row; a wave processes 4
// edges per load instruction (q = lane>>4 picks the edge). Padded edge slots
// have wgt=0 and idx=0 (row-0 loads are cache-hot, contribute nothing).
// FINAL=0: write bf16 xb (next layer input); FINAL=1: write fp32 d_out.
template <int FINAL>
__global__ __launch_bounds__(256) void agg_kernel(const ushort* __restrict__ hb,
                                                  const float* __restrict__ el,
                                                  const float* __restrict__ er,
                                                  const int* __restrict__ rowptr,
                                                  const int* __restrict__ ssrc,
                                                  const float* __restrict__ bias,
                                                  void* __restrict__ outv, int M) {
  int wid = (blockIdx.x * blockDim.x + threadIdx.x) >> 6;  // node id
  int lane = threadIdx.x & 63;
  if (wid >= M) return;
  int begin = rowptr[wid], end = rowptr[wid + 1];
  int deg = end - begin;

  if (deg > 64) {  // rare high-degree path: self-contained, float2-per-lane
    float er_d = er[wid];
    float mx = -1e30f;
    for (int e = begin + lane; e < end; e += 64) {
      float s = el[ssrc[e]] + er_d;
      s = s > 0.f ? s : 0.2f * s;
      mx = fmaxf(mx, s);
    }
#pragma unroll
    for (int off = 32; off; off >>= 1) mx = fmaxf(mx, __shfl_xor(mx, off));
    float acc0 = 0.f, acc1 = 0.f, ssum_l = 0.f;
    for (int base = begin; base < end; base += 64) {
      int n = min(64, end - base);
      int e = base + lane;
      int idx = 0;
      float wgt = 0.f;
      if (lane < n) {
        idx = ssrc[e];
        float sc = el[idx] + er_d;
        sc = sc > 0.f ? sc : 0.2f * sc;
        wgt = __expf(sc - mx);
      }
      ssum_l += wgt;
      for (int j = 0; j < n; ++j) {
        int s = __shfl(idx, j);
        float wg = __shfl(wgt, j);
        uint u = ((const uint*)(hb + (size_t)s * DH))[lane];
        acc0 += wg * bfl2f(u);
        acc1 += wg * bfh2f(u);
      }
    }
#pragma unroll
    for (int off = 32; off; off >>= 1) ssum_l += __shfl_xor(ssum_l, off);
    float inv = 1.f / ssum_l;
    float2 b2 = ((const float2*)bias)[lane];
    float o0 = acc0 * inv + b2.x;
    float o1 = acc1 * inv + b2.y;
    if constexpr (FINAL) {
      ((float2*)((float*)outv + (size_t)wid * DH))[lane] = make_float2(o0, o1);
    } else {
      uint p = (uint)f2bf(o0) | ((uint)f2bf(o1) << 16);
      ((uint*)((ushort*)outv + (size_t)wid * DH))[lane] = p;
    }
    return;
  }

  float acc[8] = {};
  float inv = 0.f;
  if (deg > 0) {
    // lane j owns edge begin+j: index, el-gather, leaky, exp all lane-parallel
    int e = begin + lane;
    int idx = (e < end) ? ssrc[e] : 0;
    float sc = -1e30f;
    if (e < end) {
      sc = el[idx] + er[wid];
      sc = sc > 0.f ? sc : 0.2f * sc;
    }
    float mx = sc;
#pragma unroll
    for (int off = 32; off; off >>= 1) mx = fmaxf(mx, __shfl_xor(mx, off));
    float wgt = (e < end) ? __expf(sc - mx) : 0.f;
    float ssum = wgt;
#pragma unroll
    for (int off = 32; off; off >>= 1) ssum += __shfl_xor(ssum, off);
    inv = 1.f / ssum;

    int q = lane >> 4, cl = lane & 15;
    const uint4* hb4 = (const uint4*)hb;  // row = 16 uint4
    for (int j = 0; j < deg; j += 16) {  // 16 edges per step (4 quads in flight)
      uint4 u[4];
      float wq[4];
#pragma unroll
      for (int k = 0; k < 4; ++k) {
        int ej = j + k * 4 + q;  // < 64 guaranteed (deg<=64, j<=48)
        int s = __shfl(idx, ej);
        wq[k] = __shfl(wgt, ej);
        u[k] = hb4[(size_t)s * 16 + cl];
      }
#pragma unroll
      for (int k = 0; k < 4; ++k) {
        acc[0] += wq[k] * bfl2f(u[k].x); acc[1] += wq[k] * bfh2f(u[k].x);
        acc[2] += wq[k] * bfl2f(u[k].y); acc[3] += wq[k] * bfh2f(u[k].y);
        acc[4] += wq[k] * bfl2f(u[k].z); acc[5] += wq[k] * bfh2f(u[k].z);
        acc[6] += wq[k] * bfl2f(u[k].w); acc[7] += wq[k] * bfh2f(u[k].w);
      }
    }
    // combine the 4 edge-quarters: lanes sharing (lane&15) sum up
#pragma unroll
    for (int i = 0; i < 8; ++i) {
      acc[i] += __shfl_xor(acc[i], 16);
      acc[i] += __shfl_xor(acc[i], 32);
    }
  }
  // deg==0: acc=0, inv=0 -> out = bias
  if (lane < 16) {
    float4 b0 = ((const float4*)bias)[lane * 2];
    float4 b1 = ((const float4*)bias)[lane * 2 + 1];
    float o[8];
    o[0] = acc[0] * inv + b0.x; o[1] = acc[1] * inv + b0.y;
    o[2] = acc[2] * inv + b0.z; o[3] = acc[3] * inv + b0.w;
    o[4] = acc[4] * inv + b1.x; o[5] = acc[5] * inv + b1.y;
    o[6] = acc[6] * inv + b1.z; o[7] = acc[7] * inv + b1.w;
    if constexpr (FINAL) {
      float* op = (float*)outv + (size_t)wid * DH + lane * 8;
      *(float4*)op = make_float4(o[0], o[1], o[2], o[3]);
      *(float4*)(op + 4) = make_float4(o[4], o[5], o[6], o[7]);
    } else {
      uint4 p;
      p.x = (uint)f2bf(o[0]) | ((uint)f2bf(o[1]) << 16);
      p.y = (uint)f2bf(o[2]) | ((uint)f2bf(o[3]) << 16);
      p.z = (uint)f2bf(o[4]) | ((uint)f2bf(o[5]) << 16);
      p.w = (uint)f2bf(o[6]) | ((uint)f2bf(o[7]) << 16);
      ((uint4*)((ushort*)outv + (size_t)wid * DH))[lane] = p;
    }
  }
}

extern "C" void kernel_launch(void* const* d_in, const int* in_sizes, int n_in,
                              void* d_out, int out_size, void* d_ws, size_t ws_size,
                              hipStream_t stream) {
  const float* feat = (const float*)d_in[0];
  const int* src = (const int*)d_in[1];
  const int* dst = (const int*)d_in[2];
  const int N = in_sizes[0] / DH;  // 100000
  const int E = in_sizes[1];       // 1600000
  const int NB = (N + 127) >> 7;   // 782 coarse bins
  const float* W[3]  = {(const float*)d_in[3], (const float*)d_in[7],  (const float*)d_in[11]};
  const float* al[3] = {(const float*)d_in[4], (const float*)d_in[8],  (const float*)d_in[12]};
  const float* ar[3] = {(const float*)d_in[5], (const float*)d_in[9],  (const float*)d_in[13]};
  const float* bi[3] = {(const float*)d_in[6], (const float*)d_in[10], (const float*)d_in[14]};

  // workspace layout (~59 MB)
  char* ws = (char*)d_ws;
  size_t off = 0;
  auto alloc = [&](size_t bytes) {
    void* p = ws + off;
    off = (off + bytes + 255) & ~(size_t)255;
    return p;
  };
  ushort* hb   = (ushort*)alloc((size_t)N * DH * sizeof(ushort));  // 25.6 MB
  ushort* xb   = (ushort*)alloc((size_t)N * DH * sizeof(ushort));  // 25.6 MB
  float* el    = (float*)alloc((size_t)N * sizeof(float));
  float* er    = (float*)alloc((size_t)N * sizeof(float));
  int* rowptr  = (int*)alloc((size_t)(N + 1) * sizeof(int));
  int* ssrc    = (int*)alloc((size_t)E * sizeof(int));             // 6.4 MB
  ushort* Wtb  = (ushort*)alloc((size_t)DH * DH * sizeof(ushort));
  int* chist   = (int*)alloc((size_t)NBMAX * 16 * sizeof(int));    // 64 KB padded
  int* cbase   = (int*)alloc((size_t)(NBMAX + 1) * sizeof(int));
  int* ccur    = (int*)alloc((size_t)NBMAX * 16 * sizeof(int));    // 64 KB padded
  uint* puv    = (uint*)hb;  // 6.4 MB alias: dead before first gemm writes hb

  // ---- CSR by dst (shared by all 3 layers): LDS-binned counting sort ----
  hipMemsetAsync(chist, 0, (size_t)NBMAX * 16 * sizeof(int), stream);
  int ebl = (E + BCH - 1) / BCH;  // 196
  chist_kernel<<<ebl, 256, 0, stream>>>(dst, chist, E, NB);
  cscan_kernel<<<1, 256, 0, stream>>>(chist, cbase, ccur, rowptr, N, NB, E);
  binscat_kernel<<<ebl, 256, 0, stream>>>(src, dst, ccur, puv, E, NB);
  finesort_kernel<<<NB, 256, 0, stream>>>(puv, cbase, rowptr, ssrc, N);

  // ---- 3 GAT layers; xb (bf16) is the inter-layer node buffer ----
  for (int l = 0; l < 3; ++l) {
    wt_kernel<<<64, 256, 0, stream>>>(W[l], Wtb);
    if (l == 0)
      gemm_kernel<true><<<(N + 63) / 64, 256, 0, stream>>>(feat, Wtb, al[l], ar[l], hb, el, er, N);
    else
      gemm_kernel<false><<<(N + 63) / 64, 256, 0, stream>>>(xb, Wtb, al[l], ar[l], hb, el, er, N);
    if (l < 2)
      agg_kernel<0><<<(N + 3) / 4, 256, 0, stream>>>(hb, el, er, rowptr, ssrc, bi[l], xb, N);
    else
      agg_kernel<1><<<(N + 3) / 4, 256, 0, stream>>>(hb, el, er, rowptr, ssrc, bi[l], d_out, N);
  }
}